// Round 3
// baseline (1274.111 us; speedup 1.0000x reference)
//
#include <hip/hip_runtime.h>
#include <math.h>

#define B_  32
#define TX_ 512
#define TY_ 2048
#define NF_ 80
#define NEGF (-1e9f)

typedef unsigned long long u64;

static constexpr float LOG2PI_F = 1.8378770664093453f;
// -0.5 * log(2*pi) * NF
static constexpr float CONST_F = (float)(-0.5 * 1.8378770664093454966 * 80.0);

// ---------------- block reduce (sum), valid on thread 0 ----------------
__device__ inline float block_reduce_sum(float v) {
    __shared__ float sred[8];
    const int lane = threadIdx.x & 63, w = threadIdx.x >> 6;
    #pragma unroll
    for (int o = 32; o; o >>= 1) v += __shfl_down(v, o);
    if (lane == 0) sred[w] = v;
    __syncthreads();
    float r = 0.f;
    if (threadIdx.x == 0) {
        const int nw = blockDim.x >> 6;
        for (int k = 0; k < nw; ++k) r += sred[k];
    }
    return r;
}

// ---------------- ysq[b][j] = -0.5*sum_c y^2 ; musq[b][i] = -0.5*sum_c mu^2 ----
__global__ __launch_bounds__(256) void sq_kernel(
    const float* __restrict__ mu, const float* __restrict__ yy,
    float* __restrict__ musq, float* __restrict__ ysq)
{
    const int t = blockIdx.x * 256 + threadIdx.x;
    const int nY = B_ * TY_;
    if (t < nY) {
        const int b = t >> 11, j = t & (TY_ - 1);
        const float* p = yy + (size_t)b * NF_ * TY_ + j;
        float s = 0.f;
        #pragma unroll 8
        for (int k = 0; k < NF_; ++k) { float v = p[(size_t)k * TY_]; s = fmaf(v, v, s); }
        ysq[t] = -0.5f * s;
    } else {
        const int t2 = t - nY;
        if (t2 < B_ * TX_) {
            const int b = t2 >> 9, i = t2 & (TX_ - 1);
            const float* p = mu + (size_t)b * NF_ * TX_ + i;
            float s = 0.f;
            #pragma unroll 8
            for (int k = 0; k < NF_; ++k) { float v = p[(size_t)k * TX_]; s = fmaf(v, v, s); }
            musq[t2] = -0.5f * s;
        }
    }
}

// ---------------- lp[b][j][i] = masked log-prior (transposed layout) ----------
__global__ __launch_bounds__(256) void lp_kernel(
    const float* __restrict__ mu, const float* __restrict__ yy,
    const float* __restrict__ musq, const float* __restrict__ ysq,
    const int* __restrict__ xl, const int* __restrict__ yl,
    float* __restrict__ lp)
{
    __shared__ float smu[NF_][64];
    __shared__ float sy[NF_][64];
    const int b  = blockIdx.z;
    const int j0 = blockIdx.y * 64;
    const int ylen = yl[b];
    if (j0 >= ylen) return;                 // rows >= ylen are never read by DP
    const int i0 = blockIdx.x * 64;
    const int tid = threadIdx.x;

    const float* mub = mu + (size_t)b * NF_ * TX_ + i0;
    const float* yb  = yy + (size_t)b * NF_ * TY_ + j0;
    for (int t = tid; t < NF_ * 64; t += 256) {
        const int k = t >> 6, c = t & 63;
        smu[k][c] = mub[(size_t)k * TX_ + c];
        sy[k][c]  = yb[(size_t)k * TY_ + c];
    }
    __syncthreads();

    const int tx = tid & 15, ty = tid >> 4;
    float acc[4][4] = {};
    #pragma unroll 8
    for (int k = 0; k < NF_; ++k) {
        const float4 av = *(const float4*)&smu[k][tx * 4];
        const float4 bv = *(const float4*)&sy[k][ty * 4];
        const float a[4]  = {av.x, av.y, av.z, av.w};
        const float bb[4] = {bv.x, bv.y, bv.z, bv.w};
        #pragma unroll
        for (int r = 0; r < 4; ++r)
            #pragma unroll
            for (int c = 0; c < 4; ++c)
                acc[r][c] = fmaf(bb[r], a[c], acc[r][c]);
    }

    const int xlen = xl[b];
    float mq[4];
    #pragma unroll
    for (int c = 0; c < 4; ++c) mq[c] = musq[b * TX_ + i0 + tx * 4 + c];

    #pragma unroll
    for (int r = 0; r < 4; ++r) {
        const int j = j0 + ty * 4 + r;
        const float base = ysq[b * TY_ + j] + CONST_F;
        float4 o;
        float* po = &o.x;
        #pragma unroll
        for (int c = 0; c < 4; ++c) {
            const int i = i0 + tx * 4 + c;
            const float val = acc[r][c] + base + mq[c];
            po[c] = (i < xlen && j < ylen) ? val : NEGF;
        }
        *(float4*)&lp[((size_t)b * TY_ + j) * TX_ + i0 + tx * 4] = o;
    }
}

// ---------------- Viterbi DP + chunked backtrack, one wave per batch ----------
// Dynamic LDS: dirs[TY_*64] bytes + durs[TX_] ints + stg[112] u64
__global__ __launch_bounds__(64) void dp_kernel(
    const float* __restrict__ lp, const int* __restrict__ xl, const int* __restrict__ yl,
    int* __restrict__ idx_out, int* __restrict__ dur_out)
{
    extern __shared__ unsigned char smem[];
    unsigned char* dirs = smem;                               // [TY_][64] (1 bit per i)
    int* durs = (int*)(smem + (size_t)TY_ * 64);              // [TX_]
    u64* stg  = (u64*)(smem + (size_t)TY_ * 64 + TX_ * 4);    // [112]

    const int b = blockIdx.x;
    const int lane = threadIdx.x;
    const int xlen = xl[b], ylen = yl[b];
    const int last = ylen - 1;                 // rows 1..last carry real DP steps

    #pragma unroll
    for (int u = 0; u < TX_ / 64; ++u) durs[lane + u * 64] = 0;
    dirs[lane] = 0;                            // row j=0: no diagonal moves

    const float* lpb = lp + (size_t)b * TY_ * TX_ + lane * 8;

    float v[8];
    #pragma unroll
    for (int u = 0; u < 8; ++u) v[u] = NEGF;
    if (lane == 0) v[0] = lp[(size_t)b * TY_ * TX_];   // j=0: only i==0 valid

    // 8-deep row prefetch (rows 1..8 always exist: ylen >= 1024)
    float4 pf[8][2];
    #pragma unroll
    for (int u = 0; u < 8; ++u) {
        const float* r = lpb + (size_t)(1 + u) * TX_;
        pf[u][0] = *(const float4*)r;
        pf[u][1] = *(const float4*)(r + 4);
    }

    auto step = [&](int j, float4 lo, float4 hi) {
        const float lv[8] = {lo.x, lo.y, lo.z, lo.w, hi.x, hi.y, hi.z, hi.w};
        float left = __shfl_up(v[7], 1);
        if (lane == 0) left = NEGF;
        float prev = left;
        unsigned bits = 0u;
        #pragma unroll
        for (int u2 = 0; u2 < 8; ++u2) {
            const float vu = v[u2];
            if (prev >= vu) bits |= (1u << u2);
            v[u2] = lv[u2] + fmaxf(vu, prev);
            prev = vu;
        }
        dirs[j * 64 + lane] = (unsigned char)bits;
    };

    // Shift-invariant renormalization: subtract the wave-uniform max from all v.
    // Keeps |v| small so fp32 decisions track an fp64 reference (ULP ~1e-4 vs 1.6e-2).
    auto renorm = [&]() {
        float m = v[0];
        #pragma unroll
        for (int u = 1; u < 8; ++u) m = fmaxf(m, v[u]);
        #pragma unroll
        for (int o = 1; o < 64; o <<= 1) m = fmaxf(m, __shfl_xor(m, o));
        #pragma unroll
        for (int u = 0; u < 8; ++u) v[u] -= m;
    };

    int j = 1;
    while (j + 7 <= last) {
        #pragma unroll
        for (int u = 0; u < 8; ++u) {
            const float4 lo = pf[u][0], hi = pf[u][1];
            const int jn = j + u + 8;
            if (jn <= last) {
                const float* r = lpb + (size_t)jn * TX_;
                pf[u][0] = *(const float4*)r;
                pf[u][1] = *(const float4*)(r + 4);
            }
            step(j + u, lo, hi);
        }
        renorm();
        j += 8;
    }
    for (int u = 0; j <= last; ++j, ++u) step(j, pf[u][0], pf[u][1]);

    __syncthreads();

    // ---- backtrack: 56-row chunks, direction window staged to LDS, all lanes
    // redundantly chase the path with static-address loads ----
    int* iout = idx_out + b * TY_;
    for (int jj = ylen + lane; jj < TY_; jj += 64) iout[jj] = -1;

    int idx = xlen - 1;
    int cnt = 0;
    int j0 = last;
    while (j0 >= 0) {
        const int n = (j0 + 1 < 56) ? (j0 + 1) : 56;
        const int A = min(max((idx >> 6) - 1, 0), 6) * 64;  // 128-col window start
        if (lane < n) {
            const unsigned char* rp = &dirs[(j0 - lane) * 64 + (A >> 3)];
            stg[lane * 2]     = *(const u64*)rp;
            stg[lane * 2 + 1] = *(const u64*)(rp + 8);
        }
        __syncthreads();
        for (int u = 0; u < n; ++u) {             // uniform across lanes
            if (lane == 0) iout[j0 - u] = idx;
            const int sh = idx - A;
            const u64 w = (sh < 64) ? stg[u * 2] : stg[u * 2 + 1];
            const int bit = (int)((w >> (sh & 63)) & 1ULL);
            ++cnt;
            if (bit) { if (lane == 0) durs[idx] = cnt; cnt = 0; --idx; }
        }
        j0 -= n;
        __syncthreads();
    }
    if (lane == 0) durs[idx] = cnt;               // flush final run
    __syncthreads();

    #pragma unroll
    for (int u = 0; u < TX_ / 64; ++u)
        dur_out[b * TX_ + lane + u * 64] = durs[lane + u * 64];
}

// ---------------- scatter one-hot attention --------------------------------
__global__ __launch_bounds__(256) void attn_kernel(
    const int* __restrict__ idxs, float* __restrict__ attn /* out+2 */)
{
    const int i = blockIdx.x;   // TX
    const int b = blockIdx.y;
    const int t = threadIdx.x;  // 8 j's per thread
    const int4* ib = (const int4*)(idxs + b * TY_);
    float* ob = attn + ((size_t)b * TX_ + i) * TY_ + t * 8;
    const int4 q0 = ib[t * 2];
    const int4 q1 = ib[t * 2 + 1];
    ((float2*)ob)[0] = make_float2(q0.x == i ? 1.f : 0.f, q0.y == i ? 1.f : 0.f);
    ((float2*)ob)[1] = make_float2(q0.z == i ? 1.f : 0.f, q0.w == i ? 1.f : 0.f);
    ((float2*)ob)[2] = make_float2(q1.x == i ? 1.f : 0.f, q1.y == i ? 1.f : 0.f);
    ((float2*)ob)[3] = make_float2(q1.z == i ? 1.f : 0.f, q1.w == i ? 1.f : 0.f);
}

// ---------------- duration loss numerator ----------------------------------
__global__ __launch_bounds__(512) void dloss_kernel(
    const float* __restrict__ logw, const int* __restrict__ dur,
    const int* __restrict__ xl, double* __restrict__ acc)
{
    const int b = blockIdx.x;
    const int i = threadIdx.x;
    float s = 0.f;
    if (i < xl[b]) {
        const float lw  = logw[b * TX_ + i];
        const float lw_ = logf(1e-8f + (float)dur[b * TX_ + i]);
        const float d = lw - lw_;
        s = d * d;
    }
    const float r = block_reduce_sum(s);
    if (threadIdx.x == 0) atomicAdd(acc + 0, (double)r);
}

// ---------------- prior loss numerator -------------------------------------
__global__ __launch_bounds__(256) void ploss_kernel(
    const float* __restrict__ mu, const float* __restrict__ yy,
    const int* __restrict__ idxs, const int* __restrict__ yl,
    double* __restrict__ acc)
{
    const int b = blockIdx.y;
    const int j = blockIdx.x * 256 + threadIdx.x;
    float s = 0.f;
    if (j < yl[b]) {
        const int ii = idxs[b * TY_ + j];
        const float* yp = yy + (size_t)b * NF_ * TY_ + j;
        const float* mp = mu + (size_t)b * NF_ * TX_ + ii;
        float sq = 0.f;
        #pragma unroll 8
        for (int k = 0; k < NF_; ++k) {
            const float d = yp[(size_t)k * TY_] - mp[(size_t)k * TX_];
            sq = fmaf(d, d, sq);
        }
        s = 0.5f * (sq + (float)NF_ * LOG2PI_F);
    }
    const float r = block_reduce_sum(s);
    if (threadIdx.x == 0) atomicAdd(acc + 1, (double)r);
}

// ---------------- finalize: divide and write the two scalars ----------------
__global__ void fin_kernel(const double* __restrict__ acc,
                           const int* __restrict__ xl, const int* __restrict__ yl,
                           float* __restrict__ out)
{
    if (threadIdx.x == 0 && blockIdx.x == 0) {
        long long sx = 0, sy = 0;
        for (int b = 0; b < B_; ++b) { sx += xl[b]; sy += yl[b]; }
        out[0] = (float)(acc[0] / (double)sx);
        out[1] = (float)(acc[1] / ((double)sy * (double)NF_));
    }
}

extern "C" void kernel_launch(void* const* d_in, const int* in_sizes, int n_in,
                              void* d_out, int out_size, void* d_ws, size_t ws_size,
                              hipStream_t stream)
{
    const float* mu   = (const float*)d_in[0];
    const float* logw = (const float*)d_in[1];
    const float* yy   = (const float*)d_in[2];
    const int*   xl   = (const int*)d_in[3];
    const int*   yl   = (const int*)d_in[4];
    float* out = (float*)d_out;

    char* ws = (char*)d_ws;
    float*  ysq  = (float*)(ws);                      // B*TY f32   (256 KiB)
    float*  musq = (float*)(ws + 262144);             // B*TX f32   (64 KiB)
    int*    idxs = (int*)  (ws + 327680);             // B*TY i32   (256 KiB)
    int*    dur  = (int*)  (ws + 589824);             // B*TX i32   (64 KiB)
    double* acc  = (double*)(ws + 655360);            // 2 f64

    float* lpbuf = out;      // [B][TY][TX] scratch over the attn region
    float* attn  = out + 2;  // final [B][TX][TY] output (8B-aligned -> float2)

    const size_t dp_lds = (size_t)TY_ * 64 + TX_ * 4 + 112 * 8;  // 134016 B

    hipMemsetAsync(acc, 0, 16, stream);
    sq_kernel<<<dim3((B_ * (TY_ + TX_) + 255) / 256), 256, 0, stream>>>(mu, yy, musq, ysq);
    lp_kernel<<<dim3(TX_ / 64, TY_ / 64, B_), 256, 0, stream>>>(mu, yy, musq, ysq, xl, yl, lpbuf);
    dp_kernel<<<dim3(B_), 64, dp_lds, stream>>>(lpbuf, xl, yl, idxs, dur);
    attn_kernel<<<dim3(TX_, B_), 256, 0, stream>>>(idxs, attn);
    dloss_kernel<<<dim3(B_), 512, 0, stream>>>(logw, dur, xl, acc);
    ploss_kernel<<<dim3(TY_ / 256, B_), 256, 0, stream>>>(mu, yy, idxs, yl, acc);
    fin_kernel<<<1, 64, 0, stream>>>(acc, xl, yl, out);
}

// Round 4
// 1245.370 us; speedup vs baseline: 1.0231x; 1.0231x over previous
//
#include <hip/hip_runtime.h>
#include <math.h>

#define B_  32
#define TX_ 512
#define TY_ 2048
#define NF_ 80
#define NEGF (-1e9f)

typedef unsigned long long u64;

static constexpr float LOG2PI_F = 1.8378770664093453f;
// -0.5 * log(2*pi) * NF
static constexpr float CONST_F = (float)(-0.5 * 1.8378770664093454966 * 80.0);

// ---------------- block reduce (sum), valid on thread 0 ----------------
__device__ inline float block_reduce_sum(float v) {
    __shared__ float sred[8];
    const int lane = threadIdx.x & 63, w = threadIdx.x >> 6;
    #pragma unroll
    for (int o = 32; o; o >>= 1) v += __shfl_down(v, o);
    if (lane == 0) sred[w] = v;
    __syncthreads();
    float r = 0.f;
    if (threadIdx.x == 0) {
        const int nw = blockDim.x >> 6;
        for (int k = 0; k < nw; ++k) r += sred[k];
    }
    return r;
}

// ---------------- ysq[b][j] = -0.5*sum_c y^2 ; musq[b][i] = -0.5*sum_c mu^2 ----
__global__ __launch_bounds__(256) void sq_kernel(
    const float* __restrict__ mu, const float* __restrict__ yy,
    float* __restrict__ musq, float* __restrict__ ysq)
{
    const int t = blockIdx.x * 256 + threadIdx.x;
    const int nY = B_ * TY_;
    if (t < nY) {
        const int b = t >> 11, j = t & (TY_ - 1);
        const float* p = yy + (size_t)b * NF_ * TY_ + j;
        float s = 0.f;
        #pragma unroll 8
        for (int k = 0; k < NF_; ++k) { float v = p[(size_t)k * TY_]; s = fmaf(v, v, s); }
        ysq[t] = -0.5f * s;
    } else {
        const int t2 = t - nY;
        if (t2 < B_ * TX_) {
            const int b = t2 >> 9, i = t2 & (TX_ - 1);
            const float* p = mu + (size_t)b * NF_ * TX_ + i;
            float s = 0.f;
            #pragma unroll 8
            for (int k = 0; k < NF_; ++k) { float v = p[(size_t)k * TX_]; s = fmaf(v, v, s); }
            musq[t2] = -0.5f * s;
        }
    }
}

// ---------------- lp[b][j][i] = masked log-prior (transposed layout) ----------
__global__ __launch_bounds__(256) void lp_kernel(
    const float* __restrict__ mu, const float* __restrict__ yy,
    const float* __restrict__ musq, const float* __restrict__ ysq,
    const int* __restrict__ xl, const int* __restrict__ yl,
    float* __restrict__ lp)
{
    __shared__ float smu[NF_][64];
    __shared__ float sy[NF_][64];
    const int b  = blockIdx.z;
    const int j0 = blockIdx.y * 64;
    const int ylen = yl[b];
    if (j0 >= ylen) return;                 // rows >= ylen are never read by DP
    const int i0 = blockIdx.x * 64;
    const int tid = threadIdx.x;

    const float* mub = mu + (size_t)b * NF_ * TX_ + i0;
    const float* yb  = yy + (size_t)b * NF_ * TY_ + j0;
    for (int t = tid; t < NF_ * 64; t += 256) {
        const int k = t >> 6, c = t & 63;
        smu[k][c] = mub[(size_t)k * TX_ + c];
        sy[k][c]  = yb[(size_t)k * TY_ + c];
    }
    __syncthreads();

    const int tx = tid & 15, ty = tid >> 4;
    float acc[4][4] = {};
    #pragma unroll 8
    for (int k = 0; k < NF_; ++k) {
        const float4 av = *(const float4*)&smu[k][tx * 4];
        const float4 bv = *(const float4*)&sy[k][ty * 4];
        const float a[4]  = {av.x, av.y, av.z, av.w};
        const float bb[4] = {bv.x, bv.y, bv.z, bv.w};
        #pragma unroll
        for (int r = 0; r < 4; ++r)
            #pragma unroll
            for (int c = 0; c < 4; ++c)
                acc[r][c] = fmaf(bb[r], a[c], acc[r][c]);
    }

    const int xlen = xl[b];
    float mq[4];
    #pragma unroll
    for (int c = 0; c < 4; ++c) mq[c] = musq[b * TX_ + i0 + tx * 4 + c];

    #pragma unroll
    for (int r = 0; r < 4; ++r) {
        const int j = j0 + ty * 4 + r;
        const float base = ysq[b * TY_ + j] + CONST_F;
        float4 o;
        float* po = &o.x;
        #pragma unroll
        for (int c = 0; c < 4; ++c) {
            const int i = i0 + tx * 4 + c;
            const float val = acc[r][c] + base + mq[c];
            po[c] = (i < xlen && j < ylen) ? val : NEGF;
        }
        *(float4*)&lp[((size_t)b * TY_ + j) * TX_ + i0 + tx * 4] = o;
    }
}

// ---------------- Viterbi DP + chunked backtrack, one wave per batch ----------
// Dynamic LDS: dirs[TY_*64] bytes + durs[TX_] ints + stg[112] u64
__global__ __launch_bounds__(64) void dp_kernel(
    const float* __restrict__ lp, const int* __restrict__ xl, const int* __restrict__ yl,
    int* __restrict__ idx_out, int* __restrict__ dur_out)
{
    extern __shared__ unsigned char smem[];
    unsigned char* dirs = smem;                               // [TY_][64] (1 bit per i)
    int* durs = (int*)(smem + (size_t)TY_ * 64);              // [TX_]
    u64* stg  = (u64*)(smem + (size_t)TY_ * 64 + TX_ * 4);    // [112]

    const int b = blockIdx.x;
    const int lane = threadIdx.x;
    const int xlen = xl[b], ylen = yl[b];
    const int last = ylen - 1;                 // rows 1..last carry real DP steps

    #pragma unroll
    for (int u = 0; u < TX_ / 64; ++u) durs[lane + u * 64] = 0;
    dirs[lane] = 0;                            // row j=0: no diagonal moves

    const float* lpb = lp + (size_t)b * TY_ * TX_ + lane * 8;

    float v[8];
    #pragma unroll
    for (int u = 0; u < 8; ++u) v[u] = NEGF;
    if (lane == 0) v[0] = lp[(size_t)b * TY_ * TX_];   // j=0: only i==0 valid

    // 8-deep row prefetch (rows 1..8 always exist: ylen >= 1024)
    float4 pf[8][2];
    #pragma unroll
    for (int u = 0; u < 8; ++u) {
        const float* r = lpb + (size_t)(1 + u) * TX_;
        pf[u][0] = *(const float4*)r;
        pf[u][1] = *(const float4*)(r + 4);
    }

    // One DP row. Shuffle issued first, consumed last (cols 1..7 are
    // shuffle-independent) so ds_bpermute latency hides behind ALU work.
    auto step = [&](int j, float4 lo, float4 hi) {
        const float lv[8] = {lo.x, lo.y, lo.z, lo.w, hi.x, hi.y, hi.z, hi.w};
        float left = __shfl_up(v[7], 1);
        unsigned bits = 0u;
        float nv[8];
        #pragma unroll
        for (int u2 = 7; u2 >= 1; --u2) {
            const float p = v[u2 - 1];
            if (p >= v[u2]) bits |= (1u << u2);
            nv[u2] = lv[u2] + fmaxf(v[u2], p);
        }
        if (lane == 0) left = NEGF;
        if (left >= v[0]) bits |= 1u;
        nv[0] = lv[0] + fmaxf(v[0], left);
        #pragma unroll
        for (int u2 = 0; u2 < 8; ++u2) v[u2] = nv[u2];
        dirs[j * 64 + lane] = (unsigned char)bits;
    };

    // Shift-invariant renormalization: subtract the wave-uniform max from all v.
    // Keeps |v| small so fp32 decisions track the reference (ULP ~5e-4).
    auto renorm = [&]() {
        float m = v[0];
        #pragma unroll
        for (int u = 1; u < 8; ++u) m = fmaxf(m, v[u]);
        #pragma unroll
        for (int o = 1; o < 64; o <<= 1) m = fmaxf(m, __shfl_xor(m, o));
        #pragma unroll
        for (int u = 0; u < 8; ++u) v[u] -= m;
    };

    int j = 1;
    int g = 0;
    while (j + 7 <= last) {
        #pragma unroll
        for (int u = 0; u < 8; ++u) {
            const float4 lo = pf[u][0], hi = pf[u][1];
            const int jn = j + u + 8;
            if (jn <= last) {
                const float* r = lpb + (size_t)jn * TX_;
                pf[u][0] = *(const float4*)r;
                pf[u][1] = *(const float4*)(r + 4);
            }
            step(j + u, lo, hi);
        }
        if (((++g) & 3) == 0) renorm();        // every 32 rows
        j += 8;
    }
    // tail: <=7 rows remain, pf[u] holds row j+u (compile-time indices only!)
    #pragma unroll
    for (int u = 0; u < 7; ++u) {
        if (j + u <= last) step(j + u, pf[u][0], pf[u][1]);
    }

    __syncthreads();

    // ---- backtrack: 56-row chunks, direction window staged to LDS, all lanes
    // redundantly chase the path with static-address loads ----
    int* iout = idx_out + b * TY_;
    for (int jj = ylen + lane; jj < TY_; jj += 64) iout[jj] = -1;

    int idx = xlen - 1;
    int cnt = 0;
    int j0 = last;
    while (j0 >= 0) {
        const int n = (j0 + 1 < 56) ? (j0 + 1) : 56;
        const int A = min(max((idx >> 6) - 1, 0), 6) * 64;  // 128-col window start
        if (lane < n) {
            const unsigned char* rp = &dirs[(j0 - lane) * 64 + (A >> 3)];
            stg[lane * 2]     = *(const u64*)rp;
            stg[lane * 2 + 1] = *(const u64*)(rp + 8);
        }
        __syncthreads();
        for (int u = 0; u < n; ++u) {             // uniform across lanes
            if (lane == 0) iout[j0 - u] = idx;
            const int sh = idx - A;
            const u64 w = (sh < 64) ? stg[u * 2] : stg[u * 2 + 1];
            const int bit = (int)((w >> (sh & 63)) & 1ULL);
            ++cnt;
            if (bit) { if (lane == 0) durs[idx] = cnt; cnt = 0; --idx; }
        }
        j0 -= n;
        __syncthreads();
    }
    if (lane == 0) durs[idx] = cnt;               // flush final run
    __syncthreads();

    #pragma unroll
    for (int u = 0; u < TX_ / 64; ++u)
        dur_out[b * TX_ + lane + u * 64] = durs[lane + u * 64];
}

// ---------------- scatter one-hot attention --------------------------------
__global__ __launch_bounds__(256) void attn_kernel(
    const int* __restrict__ idxs, float* __restrict__ attn /* out+2 */)
{
    const int i = blockIdx.x;   // TX
    const int b = blockIdx.y;
    const int t = threadIdx.x;  // 8 j's per thread
    const int4* ib = (const int4*)(idxs + b * TY_);
    float* ob = attn + ((size_t)b * TX_ + i) * TY_ + t * 8;
    const int4 q0 = ib[t * 2];
    const int4 q1 = ib[t * 2 + 1];
    ((float2*)ob)[0] = make_float2(q0.x == i ? 1.f : 0.f, q0.y == i ? 1.f : 0.f);
    ((float2*)ob)[1] = make_float2(q0.z == i ? 1.f : 0.f, q0.w == i ? 1.f : 0.f);
    ((float2*)ob)[2] = make_float2(q1.x == i ? 1.f : 0.f, q1.y == i ? 1.f : 0.f);
    ((float2*)ob)[3] = make_float2(q1.z == i ? 1.f : 0.f, q1.w == i ? 1.f : 0.f);
}

// ---------------- duration loss numerator ----------------------------------
__global__ __launch_bounds__(512) void dloss_kernel(
    const float* __restrict__ logw, const int* __restrict__ dur,
    const int* __restrict__ xl, double* __restrict__ acc)
{
    const int b = blockIdx.x;
    const int i = threadIdx.x;
    float s = 0.f;
    if (i < xl[b]) {
        const float lw  = logw[b * TX_ + i];
        const float lw_ = logf(1e-8f + (float)dur[b * TX_ + i]);
        const float d = lw - lw_;
        s = d * d;
    }
    const float r = block_reduce_sum(s);
    if (threadIdx.x == 0) atomicAdd(acc + 0, (double)r);
}

// ---------------- prior loss numerator -------------------------------------
__global__ __launch_bounds__(256) void ploss_kernel(
    const float* __restrict__ mu, const float* __restrict__ yy,
    const int* __restrict__ idxs, const int* __restrict__ yl,
    double* __restrict__ acc)
{
    const int b = blockIdx.y;
    const int j = blockIdx.x * 256 + threadIdx.x;
    float s = 0.f;
    if (j < yl[b]) {
        const int ii = idxs[b * TY_ + j];
        const float* yp = yy + (size_t)b * NF_ * TY_ + j;
        const float* mp = mu + (size_t)b * NF_ * TX_ + ii;
        float sq = 0.f;
        #pragma unroll 8
        for (int k = 0; k < NF_; ++k) {
            const float d = yp[(size_t)k * TY_] - mp[(size_t)k * TX_];
            sq = fmaf(d, d, sq);
        }
        s = 0.5f * (sq + (float)NF_ * LOG2PI_F);
    }
    const float r = block_reduce_sum(s);
    if (threadIdx.x == 0) atomicAdd(acc + 1, (double)r);
}

// ---------------- finalize: divide and write the two scalars ----------------
__global__ void fin_kernel(const double* __restrict__ acc,
                           const int* __restrict__ xl, const int* __restrict__ yl,
                           float* __restrict__ out)
{
    if (threadIdx.x == 0 && blockIdx.x == 0) {
        long long sx = 0, sy = 0;
        for (int b = 0; b < B_; ++b) { sx += xl[b]; sy += yl[b]; }
        out[0] = (float)(acc[0] / (double)sx);
        out[1] = (float)(acc[1] / ((double)sy * (double)NF_));
    }
}

extern "C" void kernel_launch(void* const* d_in, const int* in_sizes, int n_in,
                              void* d_out, int out_size, void* d_ws, size_t ws_size,
                              hipStream_t stream)
{
    const float* mu   = (const float*)d_in[0];
    const float* logw = (const float*)d_in[1];
    const float* yy   = (const float*)d_in[2];
    const int*   xl   = (const int*)d_in[3];
    const int*   yl   = (const int*)d_in[4];
    float* out = (float*)d_out;

    char* ws = (char*)d_ws;
    float*  ysq  = (float*)(ws);                      // B*TY f32   (256 KiB)
    float*  musq = (float*)(ws + 262144);             // B*TX f32   (64 KiB)
    int*    idxs = (int*)  (ws + 327680);             // B*TY i32   (256 KiB)
    int*    dur  = (int*)  (ws + 589824);             // B*TX i32   (64 KiB)
    double* acc  = (double*)(ws + 655360);            // 2 f64

    float* lpbuf = out;      // [B][TY][TX] scratch over the attn region
    float* attn  = out + 2;  // final [B][TX][TY] output (8B-aligned -> float2)

    const size_t dp_lds = (size_t)TY_ * 64 + TX_ * 4 + 112 * 8;  // 134016 B

    hipMemsetAsync(acc, 0, 16, stream);
    sq_kernel<<<dim3((B_ * (TY_ + TX_) + 255) / 256), 256, 0, stream>>>(mu, yy, musq, ysq);
    lp_kernel<<<dim3(TX_ / 64, TY_ / 64, B_), 256, 0, stream>>>(mu, yy, musq, ysq, xl, yl, lpbuf);
    dp_kernel<<<dim3(B_), 64, dp_lds, stream>>>(lpbuf, xl, yl, idxs, dur);
    attn_kernel<<<dim3(TX_, B_), 256, 0, stream>>>(idxs, attn);
    dloss_kernel<<<dim3(B_), 512, 0, stream>>>(logw, dur, xl, acc);
    ploss_kernel<<<dim3(TY_ / 256, B_), 256, 0, stream>>>(mu, yy, idxs, yl, acc);
    fin_kernel<<<1, 64, 0, stream>>>(acc, xl, yl, out);
}

// Round 5
// 1108.533 us; speedup vs baseline: 1.1494x; 1.1234x over previous
//
#include <hip/hip_runtime.h>
#include <math.h>

#define B_  32
#define TX_ 512
#define TY_ 2048
#define NF_ 80
#define NEGF (-1e9f)

typedef unsigned long long u64;
typedef const __attribute__((address_space(1))) void* gas_t;
typedef __attribute__((address_space(3))) void* las_t;

static constexpr float LOG2PI_F = 1.8378770664093453f;
static constexpr float CONST_F = (float)(-0.5 * 1.8378770664093454966 * 80.0);

// ---------------- block reduce (sum), valid on thread 0 ----------------
__device__ inline float block_reduce_sum(float v) {
    __shared__ float sred[8];
    const int lane = threadIdx.x & 63, w = threadIdx.x >> 6;
    #pragma unroll
    for (int o = 32; o; o >>= 1) v += __shfl_down(v, o);
    if (lane == 0) sred[w] = v;
    __syncthreads();
    float r = 0.f;
    if (threadIdx.x == 0) {
        const int nw = blockDim.x >> 6;
        for (int k = 0; k < nw; ++k) r += sred[k];
    }
    return r;
}

// ---------------- ysq[b][j] = -0.5*sum_c y^2 ; musq[b][i] = -0.5*sum_c mu^2 ----
__global__ __launch_bounds__(256) void sq_kernel(
    const float* __restrict__ mu, const float* __restrict__ yy,
    float* __restrict__ musq, float* __restrict__ ysq)
{
    const int t = blockIdx.x * 256 + threadIdx.x;
    const int nY = B_ * TY_;
    if (t < nY) {
        const int b = t >> 11, j = t & (TY_ - 1);
        const float* p = yy + (size_t)b * NF_ * TY_ + j;
        float s = 0.f;
        #pragma unroll 8
        for (int k = 0; k < NF_; ++k) { float v = p[(size_t)k * TY_]; s = fmaf(v, v, s); }
        ysq[t] = -0.5f * s;
    } else {
        const int t2 = t - nY;
        if (t2 < B_ * TX_) {
            const int b = t2 >> 9, i = t2 & (TX_ - 1);
            const float* p = mu + (size_t)b * NF_ * TX_ + i;
            float s = 0.f;
            #pragma unroll 8
            for (int k = 0; k < NF_; ++k) { float v = p[(size_t)k * TX_]; s = fmaf(v, v, s); }
            musq[t2] = -0.5f * s;
        }
    }
}

// ---------------- lp[b][j][i] = masked log-prior (transposed layout) ----------
__global__ __launch_bounds__(256) void lp_kernel(
    const float* __restrict__ mu, const float* __restrict__ yy,
    const float* __restrict__ musq, const float* __restrict__ ysq,
    const int* __restrict__ xl, const int* __restrict__ yl,
    float* __restrict__ lp)
{
    __shared__ float smu[NF_][64];
    __shared__ float sy[NF_][64];
    const int b  = blockIdx.z;
    const int j0 = blockIdx.y * 64;
    const int ylen = yl[b];
    if (j0 >= ylen) return;                 // rows >= ylen are never read by DP
    const int i0 = blockIdx.x * 64;
    const int tid = threadIdx.x;

    const float* mub = mu + (size_t)b * NF_ * TX_ + i0;
    const float* yb  = yy + (size_t)b * NF_ * TY_ + j0;
    for (int t = tid; t < NF_ * 64; t += 256) {
        const int k = t >> 6, c = t & 63;
        smu[k][c] = mub[(size_t)k * TX_ + c];
        sy[k][c]  = yb[(size_t)k * TY_ + c];
    }
    __syncthreads();

    const int tx = tid & 15, ty = tid >> 4;
    float acc[4][4] = {};
    #pragma unroll 8
    for (int k = 0; k < NF_; ++k) {
        const float4 av = *(const float4*)&smu[k][tx * 4];
        const float4 bv = *(const float4*)&sy[k][ty * 4];
        const float a[4]  = {av.x, av.y, av.z, av.w};
        const float bb[4] = {bv.x, bv.y, bv.z, bv.w};
        #pragma unroll
        for (int r = 0; r < 4; ++r)
            #pragma unroll
            for (int c = 0; c < 4; ++c)
                acc[r][c] = fmaf(bb[r], a[c], acc[r][c]);
    }

    const int xlen = xl[b];
    float mq[4];
    #pragma unroll
    for (int c = 0; c < 4; ++c) mq[c] = musq[b * TX_ + i0 + tx * 4 + c];

    #pragma unroll
    for (int r = 0; r < 4; ++r) {
        const int j = j0 + ty * 4 + r;
        const float base = ysq[b * TY_ + j] + CONST_F;
        float4 o;
        float* po = &o.x;
        #pragma unroll
        for (int c = 0; c < 4; ++c) {
            const int i = i0 + tx * 4 + c;
            const float val = acc[r][c] + base + mq[c];
            po[c] = (i < xlen && j < ylen) ? val : NEGF;
        }
        *(float4*)&lp[((size_t)b * TY_ + j) * TX_ + i0 + tx * 4] = o;
    }
}

// ---------------- Viterbi DP + chunked backtrack, one wave per batch ----------
// LDS layout (dynamic, 158592 B total):
//   dirs [2048][64] bytes  (1 bit per (row,col))          131072
//   ring [12][512] floats  (lp row staging, global_load_lds) 24576
//   durs [512] int                                            2048
//   stg  [112] u64  (backtrack window staging)                 896
__global__ __launch_bounds__(64) void dp_kernel(
    const float* __restrict__ lp, const int* __restrict__ xl, const int* __restrict__ yl,
    int* __restrict__ idx_out, int* __restrict__ dur_out)
{
    extern __shared__ unsigned char smem[];
    unsigned char* dirs = smem;
    float* ring = (float*)(smem + 131072);
    int*   durs = (int*)(smem + 131072 + 24576);
    u64*   stg  = (u64*)(smem + 131072 + 24576 + 2048);

    const int b = blockIdx.x;
    const int lane = threadIdx.x;
    const int xlen = xl[b], ylen = yl[b];
    const int last = ylen - 1;                 // DP rows 1..last

    #pragma unroll
    for (int u = 0; u < TX_ / 64; ++u) durs[lane + u * 64] = 0;
    dirs[lane] = 0;                            // row j=0: no diagonal moves

    const float* lprow = lp + (size_t)b * TY_ * TX_;

    float v[8];
    #pragma unroll
    for (int u = 0; u < 8; ++u) v[u] = NEGF;
    if (lane == 0) v[0] = lprow[0];            // j=0: only i==0 valid

    // Stage one lp row (2048 B) into ring slot via 2x global_load_lds width-16:
    // each call writes LDS [base + lane*16, +16) from global src + lane*16.
    auto stage_row = [&](int row, int slot) {
        const float* src = lprow + (size_t)row * TX_ + lane * 4;
        float* dst = ring + slot * TX_;        // wave-uniform base
        __builtin_amdgcn_global_load_lds((gas_t)src,         (las_t)dst,         16, 0, 0);
        __builtin_amdgcn_global_load_lds((gas_t)(src + 256), (las_t)(dst + 256), 16, 0, 0);
    };

    // One DP row from ring slot. Shuffle issued early, consumed last.
    auto step = [&](int j, int slot) {
        const float* rp = ring + slot * TX_ + lane * 8;
        const float4 lo = *(const float4*)rp;
        const float4 hi = *(const float4*)(rp + 4);
        const float lv[8] = {lo.x, lo.y, lo.z, lo.w, hi.x, hi.y, hi.z, hi.w};
        float left = __shfl_up(v[7], 1);
        unsigned bits = 0u;
        float nv[8];
        #pragma unroll
        for (int u2 = 7; u2 >= 1; --u2) {
            const float p = v[u2 - 1];
            if (p >= v[u2]) bits |= (1u << u2);
            nv[u2] = lv[u2] + fmaxf(v[u2], p);
        }
        if (lane == 0) left = NEGF;
        if (left >= v[0]) bits |= 1u;
        nv[0] = lv[0] + fmaxf(v[0], left);
        #pragma unroll
        for (int u2 = 0; u2 < 8; ++u2) v[u2] = nv[u2];
        dirs[j * 64 + lane] = (unsigned char)bits;
    };

    // Shift-invariant renormalization (wave-uniform): keeps |v| small so fp32
    // decisions track the reference. Every 32 rows.
    auto renorm = [&]() {
        float m = v[0];
        #pragma unroll
        for (int u = 1; u < 8; ++u) m = fmaxf(m, v[u]);
        #pragma unroll
        for (int o = 1; o < 64; o <<= 1) m = fmaxf(m, __shfl_xor(m, o));
        #pragma unroll
        for (int u = 0; u < 8; ++u) v[u] -= m;
    };

    // Prologue: stage rows 1..11 into slots 0..10 (ylen >= 1024 so they exist).
    #pragma unroll
    for (int u = 0; u < 11; ++u) stage_row(1 + u, u);

    // Main loop: 4 rows/iter; slot base s cycles {0,4,8} (no wrap inside body).
    // Before row r: rows r..r+10 staged (22 loads outstanding); vmcnt(20)
    // retires exactly row r's pair. Never drains to 0 (T4 counted waits).
    int r = 1, s = 0, g = 0;
    while (r + 13 <= last) {
        #pragma unroll
        for (int i = 0; i < 4; ++i) {
            asm volatile("s_waitcnt vmcnt(20)" ::: "memory");
            const int rowi = r + i;
            const int sloti = s + i;
            if (rowi + 11 <= last) {
                int ts = sloti + 11; if (ts >= 12) ts -= 12;   // slot((rowi+11)-1)
                stage_row(rowi + 11, ts);
            }
            step(rowi, sloti);
        }
        if (((++g) & 7) == 0) renorm();
        r += 4; s += 4; if (s == 12) s = 0;
    }
    // Epilogue: <=13 rows remain, all staged; drain once.
    asm volatile("s_waitcnt vmcnt(0)" ::: "memory");
    for (; r <= last; ++r) {
        step(r, s);
        if (++s == 12) s = 0;
    }

    __syncthreads();

    // ---- backtrack: 56-row chunks, 128-col window staged to LDS, all lanes
    // redundantly chase the path with static-address loads ----
    int* iout = idx_out + b * TY_;
    for (int jj = ylen + lane; jj < TY_; jj += 64) iout[jj] = -1;

    int idx = xlen - 1;
    int cnt = 0;
    int j0 = last;
    while (j0 >= 0) {
        const int n = (j0 + 1 < 56) ? (j0 + 1) : 56;
        const int A = min(max((idx >> 6) - 1, 0), 6) * 64;  // window start
        if (lane < n) {
            const unsigned char* rp = &dirs[(j0 - lane) * 64 + (A >> 3)];
            stg[lane * 2]     = *(const u64*)rp;
            stg[lane * 2 + 1] = *(const u64*)(rp + 8);
        }
        __syncthreads();
        for (int u = 0; u < n; ++u) {             // uniform across lanes
            if (lane == 0) iout[j0 - u] = idx;
            const int sh = idx - A;
            const u64 w = (sh < 64) ? stg[u * 2] : stg[u * 2 + 1];
            const int bit = (int)((w >> (sh & 63)) & 1ULL);
            ++cnt;
            if (bit) { if (lane == 0) durs[idx] = cnt; cnt = 0; --idx; }
        }
        j0 -= n;
        __syncthreads();
    }
    if (lane == 0) durs[idx] = cnt;               // flush final run
    __syncthreads();

    #pragma unroll
    for (int u = 0; u < TX_ / 64; ++u)
        dur_out[b * TX_ + lane + u * 64] = durs[lane + u * 64];
}

// ---------------- scatter one-hot attention --------------------------------
__global__ __launch_bounds__(256) void attn_kernel(
    const int* __restrict__ idxs, float* __restrict__ attn /* out+2 */)
{
    const int i = blockIdx.x;   // TX
    const int b = blockIdx.y;
    const int t = threadIdx.x;  // 8 j's per thread
    const int4* ib = (const int4*)(idxs + b * TY_);
    float* ob = attn + ((size_t)b * TX_ + i) * TY_ + t * 8;
    const int4 q0 = ib[t * 2];
    const int4 q1 = ib[t * 2 + 1];
    ((float2*)ob)[0] = make_float2(q0.x == i ? 1.f : 0.f, q0.y == i ? 1.f : 0.f);
    ((float2*)ob)[1] = make_float2(q0.z == i ? 1.f : 0.f, q0.w == i ? 1.f : 0.f);
    ((float2*)ob)[2] = make_float2(q1.x == i ? 1.f : 0.f, q1.y == i ? 1.f : 0.f);
    ((float2*)ob)[3] = make_float2(q1.z == i ? 1.f : 0.f, q1.w == i ? 1.f : 0.f);
}

// ---------------- duration loss numerator ----------------------------------
__global__ __launch_bounds__(512) void dloss_kernel(
    const float* __restrict__ logw, const int* __restrict__ dur,
    const int* __restrict__ xl, double* __restrict__ acc)
{
    const int b = blockIdx.x;
    const int i = threadIdx.x;
    float s = 0.f;
    if (i < xl[b]) {
        const float lw  = logw[b * TX_ + i];
        const float lw_ = logf(1e-8f + (float)dur[b * TX_ + i]);
        const float d = lw - lw_;
        s = d * d;
    }
    const float r = block_reduce_sum(s);
    if (threadIdx.x == 0) atomicAdd(acc + 0, (double)r);
}

// ---------------- prior loss numerator -------------------------------------
__global__ __launch_bounds__(256) void ploss_kernel(
    const float* __restrict__ mu, const float* __restrict__ yy,
    const int* __restrict__ idxs, const int* __restrict__ yl,
    double* __restrict__ acc)
{
    const int b = blockIdx.y;
    const int j = blockIdx.x * 256 + threadIdx.x;
    float s = 0.f;
    if (j < yl[b]) {
        const int ii = idxs[b * TY_ + j];
        const float* yp = yy + (size_t)b * NF_ * TY_ + j;
        const float* mp = mu + (size_t)b * NF_ * TX_ + ii;
        float sq = 0.f;
        #pragma unroll 8
        for (int k = 0; k < NF_; ++k) {
            const float d = yp[(size_t)k * TY_] - mp[(size_t)k * TX_];
            sq = fmaf(d, d, sq);
        }
        s = 0.5f * (sq + (float)NF_ * LOG2PI_F);
    }
    const float r = block_reduce_sum(s);
    if (threadIdx.x == 0) atomicAdd(acc + 1, (double)r);
}

// ---------------- finalize: divide and write the two scalars ----------------
__global__ void fin_kernel(const double* __restrict__ acc,
                           const int* __restrict__ xl, const int* __restrict__ yl,
                           float* __restrict__ out)
{
    if (threadIdx.x == 0 && blockIdx.x == 0) {
        long long sx = 0, sy = 0;
        for (int b = 0; b < B_; ++b) { sx += xl[b]; sy += yl[b]; }
        out[0] = (float)(acc[0] / (double)sx);
        out[1] = (float)(acc[1] / ((double)sy * (double)NF_));
    }
}

extern "C" void kernel_launch(void* const* d_in, const int* in_sizes, int n_in,
                              void* d_out, int out_size, void* d_ws, size_t ws_size,
                              hipStream_t stream)
{
    const float* mu   = (const float*)d_in[0];
    const float* logw = (const float*)d_in[1];
    const float* yy   = (const float*)d_in[2];
    const int*   xl   = (const int*)d_in[3];
    const int*   yl   = (const int*)d_in[4];
    float* out = (float*)d_out;

    char* ws = (char*)d_ws;
    float*  ysq  = (float*)(ws);                      // B*TY f32   (256 KiB)
    float*  musq = (float*)(ws + 262144);             // B*TX f32   (64 KiB)
    int*    idxs = (int*)  (ws + 327680);             // B*TY i32   (256 KiB)
    int*    dur  = (int*)  (ws + 589824);             // B*TX i32   (64 KiB)
    double* acc  = (double*)(ws + 655360);            // 2 f64

    float* lpbuf = out;      // [B][TY][TX] scratch over the attn region
    float* attn  = out + 2;  // final [B][TX][TY] output (8B-aligned -> float2)

    const size_t dp_lds = 131072 + 24576 + 2048 + 896;   // 158592 B

    hipMemsetAsync(acc, 0, 16, stream);
    sq_kernel<<<dim3((B_ * (TY_ + TX_) + 255) / 256), 256, 0, stream>>>(mu, yy, musq, ysq);
    lp_kernel<<<dim3(TX_ / 64, TY_ / 64, B_), 256, 0, stream>>>(mu, yy, musq, ysq, xl, yl, lpbuf);
    dp_kernel<<<dim3(B_), 64, dp_lds, stream>>>(lpbuf, xl, yl, idxs, dur);
    attn_kernel<<<dim3(TX_, B_), 256, 0, stream>>>(idxs, attn);
    dloss_kernel<<<dim3(B_), 512, 0, stream>>>(logw, dur, xl, acc);
    ploss_kernel<<<dim3(TY_ / 256, B_), 256, 0, stream>>>(mu, yy, idxs, yl, acc);
    fin_kernel<<<1, 64, 0, stream>>>(acc, xl, yl, out);
}

// Round 6
// 772.184 us; speedup vs baseline: 1.6500x; 1.4356x over previous
//
#include <hip/hip_runtime.h>
#include <math.h>

#define B_  32
#define TX_ 512
#define TY_ 2048
#define NF_ 80
#define NEGF (-1e9f)

typedef unsigned long long u64;
typedef const __attribute__((address_space(1))) void* gas_t;
typedef __attribute__((address_space(3))) void* las_t;
typedef float f32x4 __attribute__((ext_vector_type(4)));

static constexpr float LOG2PI_F = 1.8378770664093453f;
static constexpr float CONST_F = (float)(-0.5 * 1.8378770664093454966 * 80.0);

// ---------------- block reduce (sum), valid on thread 0 ----------------
__device__ inline float block_reduce_sum(float v) {
    __shared__ float sred[8];
    const int lane = threadIdx.x & 63, w = threadIdx.x >> 6;
    #pragma unroll
    for (int o = 32; o; o >>= 1) v += __shfl_down(v, o);
    if (lane == 0) sred[w] = v;
    __syncthreads();
    float r = 0.f;
    if (threadIdx.x == 0) {
        const int nw = blockDim.x >> 6;
        for (int k = 0; k < nw; ++k) r += sred[k];
    }
    return r;
}

// ---------------- ysq[b][j] = -0.5*sum_c y^2 ; musq[b][i] = -0.5*sum_c mu^2 ----
__global__ __launch_bounds__(256) void sq_kernel(
    const float* __restrict__ mu, const float* __restrict__ yy,
    float* __restrict__ musq, float* __restrict__ ysq)
{
    const int t = blockIdx.x * 256 + threadIdx.x;
    const int nY = B_ * TY_;
    if (t < nY) {
        const int b = t >> 11, j = t & (TY_ - 1);
        const float* p = yy + (size_t)b * NF_ * TY_ + j;
        float s = 0.f;
        #pragma unroll 8
        for (int k = 0; k < NF_; ++k) { float v = p[(size_t)k * TY_]; s = fmaf(v, v, s); }
        ysq[t] = -0.5f * s;
    } else {
        const int t2 = t - nY;
        if (t2 < B_ * TX_) {
            const int b = t2 >> 9, i = t2 & (TX_ - 1);
            const float* p = mu + (size_t)b * NF_ * TX_ + i;
            float s = 0.f;
            #pragma unroll 8
            for (int k = 0; k < NF_; ++k) { float v = p[(size_t)k * TX_]; s = fmaf(v, v, s); }
            musq[t2] = -0.5f * s;
        }
    }
}

// ---------------- lp[b][j][i] = masked log-prior (transposed layout) ----------
__global__ __launch_bounds__(256) void lp_kernel(
    const float* __restrict__ mu, const float* __restrict__ yy,
    const float* __restrict__ musq, const float* __restrict__ ysq,
    const int* __restrict__ xl, const int* __restrict__ yl,
    float* __restrict__ lp)
{
    __shared__ float smu[NF_][64];
    __shared__ float sy[NF_][64];
    const int b  = blockIdx.z;
    const int j0 = blockIdx.y * 64;
    const int ylen = yl[b];
    if (j0 >= ylen) return;                 // rows >= ylen are never read by DP
    const int i0 = blockIdx.x * 64;
    const int tid = threadIdx.x;

    const float* mub = mu + (size_t)b * NF_ * TX_ + i0;
    const float* yb  = yy + (size_t)b * NF_ * TY_ + j0;
    for (int t = tid; t < NF_ * 64; t += 256) {
        const int k = t >> 6, c = t & 63;
        smu[k][c] = mub[(size_t)k * TX_ + c];
        sy[k][c]  = yb[(size_t)k * TY_ + c];
    }
    __syncthreads();

    const int tx = tid & 15, ty = tid >> 4;
    float acc[4][4] = {};
    #pragma unroll 8
    for (int k = 0; k < NF_; ++k) {
        const float4 av = *(const float4*)&smu[k][tx * 4];
        const float4 bv = *(const float4*)&sy[k][ty * 4];
        const float a[4]  = {av.x, av.y, av.z, av.w};
        const float bb[4] = {bv.x, bv.y, bv.z, bv.w};
        #pragma unroll
        for (int r = 0; r < 4; ++r)
            #pragma unroll
            for (int c = 0; c < 4; ++c)
                acc[r][c] = fmaf(bb[r], a[c], acc[r][c]);
    }

    const int xlen = xl[b];
    float mq[4];
    #pragma unroll
    for (int c = 0; c < 4; ++c) mq[c] = musq[b * TX_ + i0 + tx * 4 + c];

    #pragma unroll
    for (int r = 0; r < 4; ++r) {
        const int j = j0 + ty * 4 + r;
        const float base = ysq[b * TY_ + j] + CONST_F;
        float4 o;
        float* po = &o.x;
        #pragma unroll
        for (int c = 0; c < 4; ++c) {
            const int i = i0 + tx * 4 + c;
            const float val = acc[r][c] + base + mq[c];
            po[c] = (i < xlen && j < ylen) ? val : NEGF;
        }
        *(float4*)&lp[((size_t)b * TY_ + j) * TX_ + i0 + tx * 4] = o;
    }
}

// ---------------- Viterbi DP + chunked backtrack, one wave per batch ----------
// LDS layout (dynamic, 158592 B total — proven launchable):
//   dirs [2048][64] bytes  (1 bit per (row,col))             131072
//   ring [12][512] floats  (lp row staging, global_load_lds)  24576
//   durs [512] int                                             2048
//   stg  [112] u64  (backtrack window staging)                  896
// All in-main-loop LDS traffic is inline-asm / builtin so the compiler's
// waitcnt pass cannot insert per-row vmcnt(0) drains (round-5 lesson).
__global__ __launch_bounds__(64) void dp_kernel(
    const float* __restrict__ lp, const int* __restrict__ xl, const int* __restrict__ yl,
    int* __restrict__ idx_out, int* __restrict__ dur_out)
{
    extern __shared__ unsigned char smem[];
    unsigned char* dirs = smem;
    float* ring = (float*)(smem + 131072);
    int*   durs = (int*)(smem + 131072 + 24576);
    u64*   stg  = (u64*)(smem + 131072 + 24576 + 2048);

    const int b = blockIdx.x;
    const int lane = threadIdx.x;
    const int xlen = xl[b], ylen = yl[b];
    const int last = ylen - 1;                 // DP rows 1..last

    // All C++ LDS writes happen BEFORE any LDS-DMA is issued.
    #pragma unroll
    for (int u = 0; u < TX_ / 64; ++u) durs[lane + u * 64] = 0;
    dirs[lane] = 0;                            // row j=0: no diagonal moves

    const float* lprow = lp + (size_t)b * TY_ * TX_;

    float v[8];
    #pragma unroll
    for (int u = 0; u < 8; ++u) v[u] = NEGF;
    if (lane == 0) v[0] = lprow[0];            // j=0: only i==0 valid

    // 32-bit LDS byte offsets for inline asm.
    const unsigned ring_base = (unsigned)(uintptr_t)(las_t)ring;
    const unsigned dirs_base = (unsigned)(uintptr_t)(las_t)dirs;
    const int bpaddr = (lane - 1) * 4;         // ds_bpermute index (lane0: garbage, masked)

    // Stage one lp row (2048 B) into ring slot via 2x global_load_lds width-16.
    auto stage_row = [&](int row, int slot) {
        const float* src = lprow + (size_t)row * TX_ + lane * 4;
        float* dst = ring + slot * TX_;        // wave-uniform base
        __builtin_amdgcn_global_load_lds((gas_t)src,         (las_t)dst,         16, 0, 0);
        __builtin_amdgcn_global_load_lds((gas_t)(src + 256), (las_t)(dst + 256), 16, 0, 0);
    };

    // One DP row: counted vmcnt + ds_read + bpermute + lgkmcnt in ONE asm blob
    // (invisible to the compiler's conservative LDS-DMA hazard tracking).
    auto step = [&](int j, int slot) {
        const unsigned laddr = ring_base + (unsigned)(slot * (TX_ * 4) + lane * 32);
        f32x4 lo, hi;
        float left;
        asm volatile(
            "s_waitcnt vmcnt(22)\n\t"
            "ds_read_b128 %0, %3\n\t"
            "ds_read_b128 %1, %3 offset:16\n\t"
            "ds_bpermute_b32 %2, %4, %5\n\t"
            "s_waitcnt lgkmcnt(0)"
            : "=&v"(lo), "=&v"(hi), "=&v"(left)
            : "v"(laddr), "v"(bpaddr), "v"(v[7]));
        const float lv[8] = {lo.x, lo.y, lo.z, lo.w, hi.x, hi.y, hi.z, hi.w};
        unsigned bits = 0u;
        float nv[8];
        #pragma unroll
        for (int u2 = 7; u2 >= 1; --u2) {
            const float p = v[u2 - 1];
            if (p >= v[u2]) bits |= (1u << u2);
            nv[u2] = lv[u2] + fmaxf(v[u2], p);
        }
        if (lane == 0) left = NEGF;
        if (left >= v[0]) bits |= 1u;
        nv[0] = lv[0] + fmaxf(v[0], left);
        #pragma unroll
        for (int u2 = 0; u2 < 8; ++u2) v[u2] = nv[u2];
        const unsigned daddr = dirs_base + (unsigned)(j * 64 + lane);
        asm volatile("ds_write_b8 %0, %1" :: "v"(daddr), "v"(bits));
    };

    // Uniform-shift renorm via readfirstlane (no DS ops — avoids drain triggers).
    // Viterbi decisions are invariant under a wave-uniform subtraction; keeping
    // |v| small keeps fp32 decisions tracking the reference.
    auto renorm = [&]() {
        const float m = __int_as_float(__builtin_amdgcn_readfirstlane(__float_as_int(v[0])));
        #pragma unroll
        for (int u = 0; u < 8; ++u) v[u] -= m;
    };

    // Prologue: stage rows 1..11 into slots 0..10 (22 loads outstanding).
    #pragma unroll
    for (int u = 0; u < 11; ++u) stage_row(1 + u, u);

    // Main loop invariant (entering row r, slot s): rows r..r+10 staged.
    // stage r+11 (24 outstanding) -> blob waits vmcnt(22) = retires row r.
    int r = 1, s = 0;
    while (r + 11 <= last) {
        stage_row(r + 11, (s == 0) ? 11 : s - 1);
        __builtin_amdgcn_sched_barrier(0);
        step(r, s);
        if ((r & 31) == 0) renorm();
        ++r; s = (s + 1 == 12) ? 0 : s + 1;
    }
    // Epilogue: <=11 rows remain, all staged; drain once (blob vmcnt no-ops).
    asm volatile("s_waitcnt vmcnt(0)");
    for (; r <= last; ++r) {
        step(r, s);
        s = (s + 1 == 12) ? 0 : s + 1;
    }

    asm volatile("s_waitcnt lgkmcnt(0)");
    __builtin_amdgcn_sched_barrier(0);
    __syncthreads();

    // ---- backtrack: 56-row chunks, 128-col window staged to LDS, all lanes
    // redundantly chase the path with static-address loads ----
    int* iout = idx_out + b * TY_;
    for (int jj = ylen + lane; jj < TY_; jj += 64) iout[jj] = -1;

    int idx = xlen - 1;
    int cnt = 0;
    int j0 = last;
    while (j0 >= 0) {
        const int n = (j0 + 1 < 56) ? (j0 + 1) : 56;
        const int A = min(max((idx >> 6) - 1, 0), 6) * 64;  // window start
        if (lane < n) {
            const unsigned char* rp = &dirs[(j0 - lane) * 64 + (A >> 3)];
            stg[lane * 2]     = *(const u64*)rp;
            stg[lane * 2 + 1] = *(const u64*)(rp + 8);
        }
        __syncthreads();
        for (int u = 0; u < n; ++u) {             // uniform across lanes
            if (lane == 0) iout[j0 - u] = idx;
            const int sh = idx - A;
            const u64 w = (sh < 64) ? stg[u * 2] : stg[u * 2 + 1];
            const int bit = (int)((w >> (sh & 63)) & 1ULL);
            ++cnt;
            if (bit) { if (lane == 0) durs[idx] = cnt; cnt = 0; --idx; }
        }
        j0 -= n;
        __syncthreads();
    }
    if (lane == 0) durs[idx] = cnt;               // flush final run
    __syncthreads();

    #pragma unroll
    for (int u = 0; u < TX_ / 64; ++u)
        dur_out[b * TX_ + lane + u * 64] = durs[lane + u * 64];
}

// ---------------- scatter one-hot attention --------------------------------
__global__ __launch_bounds__(256) void attn_kernel(
    const int* __restrict__ idxs, float* __restrict__ attn /* out+2 */)
{
    const int i = blockIdx.x;   // TX
    const int b = blockIdx.y;
    const int t = threadIdx.x;  // 8 j's per thread
    const int4* ib = (const int4*)(idxs + b * TY_);
    float* ob = attn + ((size_t)b * TX_ + i) * TY_ + t * 8;
    const int4 q0 = ib[t * 2];
    const int4 q1 = ib[t * 2 + 1];
    ((float2*)ob)[0] = make_float2(q0.x == i ? 1.f : 0.f, q0.y == i ? 1.f : 0.f);
    ((float2*)ob)[1] = make_float2(q0.z == i ? 1.f : 0.f, q0.w == i ? 1.f : 0.f);
    ((float2*)ob)[2] = make_float2(q1.x == i ? 1.f : 0.f, q1.y == i ? 1.f : 0.f);
    ((float2*)ob)[3] = make_float2(q1.z == i ? 1.f : 0.f, q1.w == i ? 1.f : 0.f);
}

// ---------------- duration loss numerator ----------------------------------
__global__ __launch_bounds__(512) void dloss_kernel(
    const float* __restrict__ logw, const int* __restrict__ dur,
    const int* __restrict__ xl, double* __restrict__ acc)
{
    const int b = blockIdx.x;
    const int i = threadIdx.x;
    float s = 0.f;
    if (i < xl[b]) {
        const float lw  = logw[b * TX_ + i];
        const float lw_ = logf(1e-8f + (float)dur[b * TX_ + i]);
        const float d = lw - lw_;
        s = d * d;
    }
    const float r = block_reduce_sum(s);
    if (threadIdx.x == 0) atomicAdd(acc + 0, (double)r);
}

// ---------------- prior loss numerator -------------------------------------
__global__ __launch_bounds__(256) void ploss_kernel(
    const float* __restrict__ mu, const float* __restrict__ yy,
    const int* __restrict__ idxs, const int* __restrict__ yl,
    double* __restrict__ acc)
{
    const int b = blockIdx.y;
    const int j = blockIdx.x * 256 + threadIdx.x;
    float s = 0.f;
    if (j < yl[b]) {
        const int ii = idxs[b * TY_ + j];
        const float* yp = yy + (size_t)b * NF_ * TY_ + j;
        const float* mp = mu + (size_t)b * NF_ * TX_ + ii;
        float sq = 0.f;
        #pragma unroll 8
        for (int k = 0; k < NF_; ++k) {
            const float d = yp[(size_t)k * TY_] - mp[(size_t)k * TX_];
            sq = fmaf(d, d, sq);
        }
        s = 0.5f * (sq + (float)NF_ * LOG2PI_F);
    }
    const float r = block_reduce_sum(s);
    if (threadIdx.x == 0) atomicAdd(acc + 1, (double)r);
}

// ---------------- finalize: divide and write the two scalars ----------------
__global__ void fin_kernel(const double* __restrict__ acc,
                           const int* __restrict__ xl, const int* __restrict__ yl,
                           float* __restrict__ out)
{
    if (threadIdx.x == 0 && blockIdx.x == 0) {
        long long sx = 0, sy = 0;
        for (int b = 0; b < B_; ++b) { sx += xl[b]; sy += yl[b]; }
        out[0] = (float)(acc[0] / (double)sx);
        out[1] = (float)(acc[1] / ((double)sy * (double)NF_));
    }
}

extern "C" void kernel_launch(void* const* d_in, const int* in_sizes, int n_in,
                              void* d_out, int out_size, void* d_ws, size_t ws_size,
                              hipStream_t stream)
{
    const float* mu   = (const float*)d_in[0];
    const float* logw = (const float*)d_in[1];
    const float* yy   = (const float*)d_in[2];
    const int*   xl   = (const int*)d_in[3];
    const int*   yl   = (const int*)d_in[4];
    float* out = (float*)d_out;

    char* ws = (char*)d_ws;
    float*  ysq  = (float*)(ws);                      // B*TY f32   (256 KiB)
    float*  musq = (float*)(ws + 262144);             // B*TX f32   (64 KiB)
    int*    idxs = (int*)  (ws + 327680);             // B*TY i32   (256 KiB)
    int*    dur  = (int*)  (ws + 589824);             // B*TX i32   (64 KiB)
    double* acc  = (double*)(ws + 655360);            // 2 f64

    float* lpbuf = out;      // [B][TY][TX] scratch over the attn region
    float* attn  = out + 2;  // final [B][TX][TY] output (8B-aligned -> float2)

    const size_t dp_lds = 131072 + 24576 + 2048 + 896;   // 158592 B

    hipMemsetAsync(acc, 0, 16, stream);
    sq_kernel<<<dim3((B_ * (TY_ + TX_) + 255) / 256), 256, 0, stream>>>(mu, yy, musq, ysq);
    lp_kernel<<<dim3(TX_ / 64, TY_ / 64, B_), 256, 0, stream>>>(mu, yy, musq, ysq, xl, yl, lpbuf);
    dp_kernel<<<dim3(B_), 64, dp_lds, stream>>>(lpbuf, xl, yl, idxs, dur);
    attn_kernel<<<dim3(TX_, B_), 256, 0, stream>>>(idxs, attn);
    dloss_kernel<<<dim3(B_), 512, 0, stream>>>(logw, dur, xl, acc);
    ploss_kernel<<<dim3(TY_ / 256, B_), 256, 0, stream>>>(mu, yy, idxs, yl, acc);
    fin_kernel<<<1, 64, 0, stream>>>(acc, xl, yl, out);
}